// Round 9
// baseline (42.612 us; speedup 1.0000x reference)
//
#include <hip/hip_runtime.h>
#include <math.h>

#define NROWS 2048
#define ZROWS 4096
#define DIMS  512
#define KG    5
#define NJOBS 528    // 33*32/2 upper-tri 128x128 tiles of 4096^2

// invc[k] = 1/(2*gamma^2), gammas = {2,1,0.5,0.25,0.125} -> {0.125,0.5,2,8,32} (x4 chain)
__device__ __constant__ float c_invc[KG] = {0.125f, 0.5f, 2.0f, 8.0f, 32.0f};

typedef __attribute__((ext_vector_type(4))) int i32x4;

__device__ __forceinline__ void gload_lds16(const void* g, void* l) {
    __builtin_amdgcn_global_load_lds(
        (const __attribute__((address_space(1))) unsigned int*)g,
        (__attribute__((address_space(3))) unsigned int*)l, 16, 0, 0);
}

__device__ __forceinline__ unsigned long long pack8(const float4 v0, const float4 v1, float inv) {
    const float vv[8] = {v0.x, v0.y, v0.z, v0.w, v1.x, v1.y, v1.z, v1.w};
    unsigned long long pk = 0;
#pragma unroll
    for (int e = 0; e < 8; ++e) {
        int q = (int)rintf(vv[e] * inv);
        q = q > 127 ? 127 : (q < -127 ? -127 : q);
        pk |= (unsigned long long)((unsigned)q & 0xffu) << (8 * e);
    }
    return pk;
}

// ============ prep: int8 quantize into stacked Z + norms/scales + h pairs ============
// 256 blocks x 256 threads; one wave per pair j: rows {2j,2j+1} of BOTH Xs and Xt.
// Z rows: [0,2048) = Xs, [2048,4096) = Xt. nz/sz stacked likewise.
__global__ void prep_kernel(const float* __restrict__ Xs, const float* __restrict__ Xt,
                            signed char* __restrict__ Zq,
                            float* __restrict__ nz, float* __restrict__ sz,
                            float* __restrict__ h) {
    const int pairI = blockIdx.x * 4 + (threadIdx.x >> 6);   // 0..1023
    const int lane = threadIdx.x & 63;
    const int i = 2 * pairI, j = i + 1;

    const float* psi = Xs + (size_t)i * DIMS + lane * 8;
    const float* psj = Xs + (size_t)j * DIMS + lane * 8;
    const float* pti = Xt + (size_t)i * DIMS + lane * 8;
    const float* ptj = Xt + (size_t)j * DIMS + lane * 8;
    const float4 a0 = *(const float4*)psi, a1 = *(const float4*)(psi + 4);
    const float4 b0 = *(const float4*)psj, b1 = *(const float4*)(psj + 4);
    const float4 c0 = *(const float4*)pti, c1 = *(const float4*)(pti + 4);
    const float4 d0 = *(const float4*)ptj, d1 = *(const float4*)(ptj + 4);

#define DOT8(u0, u1, v0, v1) (u0.x*v0.x + u0.y*v0.y + u0.z*v0.z + u0.w*v0.w + \
                              u1.x*v1.x + u1.y*v1.y + u1.z*v1.z + u1.w*v1.w)
#define MAX8(u0, u1) fmaxf(fmaxf(fmaxf(fabsf(u0.x), fabsf(u0.y)), fmaxf(fabsf(u0.z), fabsf(u0.w))), \
                           fmaxf(fmaxf(fabsf(u1.x), fabsf(u1.y)), fmaxf(fabsf(u1.z), fabsf(u1.w))))
    float r[8];
    r[0] = DOT8(a0, a1, a0, a1);
    r[1] = DOT8(b0, b1, b0, b1);
    r[2] = DOT8(c0, c1, c0, c1);
    r[3] = DOT8(d0, d1, d0, d1);
    r[4] = DOT8(a0, a1, b0, b1);
    r[5] = DOT8(c0, c1, d0, d1);
    r[6] = DOT8(a0, a1, d0, d1);
    r[7] = DOT8(c0, c1, b0, b1);
    float mx[4] = {MAX8(a0, a1), MAX8(b0, b1), MAX8(c0, c1), MAX8(d0, d1)};
#undef DOT8
#undef MAX8

#pragma unroll
    for (int v = 0; v < 4; ++v)
        for (int off = 32; off > 0; off >>= 1) mx[v] = fmaxf(mx[v], __shfl_xor(mx[v], off, 64));

    float inv[4], scl[4];
#pragma unroll
    for (int v = 0; v < 4; ++v) {
        scl[v] = mx[v] * (1.f / 127.f);
        inv[v] = mx[v] > 0.f ? 127.f / mx[v] : 0.f;
    }

    *(unsigned long long*)(Zq + (size_t)i * DIMS + lane * 8)            = pack8(a0, a1, inv[0]);
    *(unsigned long long*)(Zq + (size_t)j * DIMS + lane * 8)            = pack8(b0, b1, inv[1]);
    *(unsigned long long*)(Zq + (size_t)(NROWS + i) * DIMS + lane * 8)  = pack8(c0, c1, inv[2]);
    *(unsigned long long*)(Zq + (size_t)(NROWS + j) * DIMS + lane * 8)  = pack8(d0, d1, inv[3]);

#pragma unroll
    for (int v = 0; v < 8; ++v)
        for (int off = 32; off > 0; off >>= 1) r[v] += __shfl_down(r[v], off, 64);

    if (lane == 0) {
        nz[i] = r[0]; nz[j] = r[1]; nz[NROWS + i] = r[2]; nz[NROWS + j] = r[3];
        sz[i] = scl[0]; sz[j] = scl[1]; sz[NROWS + i] = scl[2]; sz[NROWS + j] = scl[3];
#pragma unroll
        for (int g = 0; g < KG; ++g) {
            const float ic = c_invc[g];
            h[g * 1024 + pairI] = __expf(-(r[0] + r[1] - 2.f * r[4]) * ic)
                                + __expf(-(r[2] + r[3] - 2.f * r[5]) * ic)
                                - __expf(-(r[0] + r[3] - 2.f * r[6]) * ic)
                                - __expf(-(r[2] + r[1] - 2.f * r[7]) * ic);
        }
    }
}

// ============ gram: upper-tri Z.Z^T, i8 MFMA, 128x128 tiles, BK=128, dbuf LDS 64KB ============
// weight: same-quadrant off-diag +2, cross-quadrant -2 (bakes sXX+sYY-2sXY), diag +1 analytic.
// LDS row = 128 B = 8 chunks of 16 B; chunk c at slot c^(row&7); pre-swizzled global source.
__global__ __launch_bounds__(256, 2) void gram_kernel(const signed char* __restrict__ Zq,
                                                      const float* __restrict__ nz,
                                                      const float* __restrict__ sz,
                                                      float* __restrict__ partial) {
    // decode job -> (by, bx), bx >= by, 33x32/2 = 528
    int job = blockIdx.x;
    int by = 0;
    while (job >= (32 - by)) { job -= (32 - by); ++by; }
    const int bx = by + job;

    const int row0 = by * 128, col0 = bx * 128;
    const int tid = threadIdx.x;
    const int lane = tid & 63;
    const int w = tid >> 6;
    const int wr = w >> 1, wc = w & 1;               // 2x2 waves, 64x64 per wave

    __shared__ signed char Asm[2][128 * 128];        // 2 x 16 KB
    __shared__ signed char Bsm[2][128 * 128];        // 2 x 16 KB

    i32x4 acc[4][4] = {};

    const int lrow = lane >> 3;                      // 0..7 row within 8-row group
    const int lchunk = (lane & 7) ^ lrow;            // pre-swizzled source chunk

#define STAGE(buf, kt)                                                              \
    {                                                                               \
        _Pragma("unroll")                                                           \
        for (int q = 0; q < 4; ++q) {                                               \
            const int rbase = w * 32 + q * 8;                                       \
            const int rloc = rbase + lrow;                                          \
            gload_lds16(Zq + (size_t)(row0 + rloc) * DIMS + (kt) + lchunk * 16,     \
                        &Asm[buf][rbase * 128]);                                    \
            gload_lds16(Zq + (size_t)(col0 + rloc) * DIMS + (kt) + lchunk * 16,     \
                        &Bsm[buf][rbase * 128]);                                    \
        }                                                                           \
    }

    STAGE(0, 0);
    __syncthreads();

    const int rl = lane & 15, kq = lane >> 4;
#pragma unroll
    for (int t = 0; t < 4; ++t) {
        const int cur = t & 1;
        if (t < 3) STAGE(cur ^ 1, (t + 1) * 128);    // prefetch issued BEFORE compute

#pragma unroll
        for (int sub = 0; sub < 2; ++sub) {          // two K=64 sub-steps per 128 tile
            i32x4 af[4], bv[4];
#pragma unroll
            for (int m = 0; m < 4; ++m) {
                const int ra = wr * 64 + m * 16 + rl;
                af[m] = *(const i32x4*)&Asm[cur][ra * 128 + (((sub * 4 + kq) ^ (ra & 7)) * 16)];
                const int rb = wc * 64 + m * 16 + rl;
                bv[m] = *(const i32x4*)&Bsm[cur][rb * 128 + (((sub * 4 + kq) ^ (rb & 7)) * 16)];
            }
#pragma unroll
            for (int m = 0; m < 4; ++m)
#pragma unroll
                for (int n = 0; n < 4; ++n)
                    acc[m][n] = __builtin_amdgcn_mfma_i32_16x16x64_i8(af[m], bv[n], acc[m][n], 0, 0, 0);
        }
        __syncthreads();
    }
#undef STAGE

    // epilogue: C/D layout col = lane&15, row = (lane>>4)*4 + reg
    // d = |a|^2 + |b|^2 - 2*sa*sb*idot; screen d>=840 -> all 5 exps underflow f32 -> skip
    float lsum[KG] = {0.f, 0.f, 0.f, 0.f, 0.f};
    const int gcol0 = col0 + wc * 64 + rl;
    const int grow0 = row0 + wr * 64 + kq * 4;
    const bool diagTile = (bx == by);
    const bool sameQuad = ((bx < 16) == (by < 16));
    const float wgt = sameQuad ? 2.f : -2.f;

    float colnorm[4], colscale[4];
#pragma unroll
    for (int n = 0; n < 4; ++n) {
        colnorm[n] = nz[gcol0 + n * 16];
        colscale[n] = sz[gcol0 + n * 16];
    }

#pragma unroll
    for (int m = 0; m < 4; ++m) {
        const float4 rn4 = *(const float4*)&nz[grow0 + m * 16];
        const float4 rs4 = *(const float4*)&sz[grow0 + m * 16];
        const float rn[4] = {rn4.x, rn4.y, rn4.z, rn4.w};
        const float rs[4] = {rs4.x, rs4.y, rs4.z, rs4.w};
#pragma unroll
        for (int jj = 0; jj < 4; ++jj) {
            const int grow = grow0 + m * 16 + jj;
#pragma unroll
            for (int n = 0; n < 4; ++n) {
                const int gcol = gcol0 + n * 16;
                const float d = rn[jj] + colnorm[n]
                              - 2.f * (rs[jj] * colscale[n]) * (float)acc[m][n][jj];
                if (diagTile && gcol == grow) {
#pragma unroll
                    for (int g = 0; g < KG; ++g) lsum[g] += 1.f;   // exp(0) exactly
                } else if ((!diagTile || gcol > grow) && d < 840.f) {
                    float e = __expf(-d * 0.125f);                 // gamma=2
#pragma unroll
                    for (int g = 0; g < KG; ++g) {
                        lsum[g] += wgt * e;
                        const float e2 = e * e;
                        e = e2 * e2;                               // next gamma (invc x4)
                    }
                }
            }
        }
    }

    // cross-wave reduce + per-block partial store (no atomics)
    __shared__ float redf[KG][4];
#pragma unroll
    for (int g = 0; g < KG; ++g) {
        float v = lsum[g];
        for (int off = 32; off > 0; off >>= 1) v += __shfl_down(v, off, 64);
        if (lane == 0) redf[g][w] = v;
    }
    __syncthreads();
    if (tid < KG)
        partial[blockIdx.x * 8 + tid] = redf[tid][0] + redf[tid][1] + redf[tid][2] + redf[tid][3];
}

// ---------------- finalize: partial reduce, hsum, Q from h4 dots, parallel QP ----------------
__global__ void finalize_kernel(const float* __restrict__ partial,
                                const float* __restrict__ h,
                                float* __restrict__ out) {
    __shared__ float h4[KG][512];
    __shared__ float hsumS[KG];
    __shared__ float qdotS[15];
    __shared__ float redh[KG][4];
    __shared__ double redd[4][KG];
    __shared__ double sumsS[KG];
    const int t = threadIdx.x;
    const int wv = t >> 6, ln = t & 63;

    // reduce gram partials: eta numerator already weight-baked (sXX+sYY-2sXY)
    {
        double s[KG] = {0.0, 0.0, 0.0, 0.0, 0.0};
        for (int b = t; b < NJOBS; b += 256) {
            const float* p = &partial[b * 8];
#pragma unroll
            for (int g = 0; g < KG; ++g) s[g] += (double)p[g];
        }
#pragma unroll
        for (int g = 0; g < KG; ++g) {
            double v = s[g];
            for (int off = 32; off > 0; off >>= 1) v += __shfl_down(v, off, 64);
            if (ln == 0) redd[wv][g] = v;
        }
    }

    for (int k = 0; k < KG; ++k)
        for (int j2 = t; j2 < 512; j2 += 256)
            h4[k][j2] = h[k * 1024 + 2 * j2] - h[k * 1024 + 2 * j2 + 1];

    {
        float s[KG] = {0.f, 0.f, 0.f, 0.f, 0.f};
        for (int j = t; j < 1024; j += 256)
#pragma unroll
            for (int k = 0; k < KG; ++k) s[k] += h[k * 1024 + j];
#pragma unroll
        for (int k = 0; k < KG; ++k) {
            float v = s[k];
            for (int off = 32; off > 0; off >>= 1) v += __shfl_down(v, off, 64);
            if (ln == 0) redh[k][wv] = v;
        }
    }
    __syncthreads();
    if (t < KG) {
        hsumS[t] = redh[t][0] + redh[t][1] + redh[t][2] + redh[t][3];
        sumsS[t] = redd[0][t] + redd[1][t] + redd[2][t] + redd[3][t];
    }
    __syncthreads();

    const int pa[15] = {0,0,0,0,0,1,1,1,1,2,2,2,3,3,4};
    const int pb[15] = {0,1,2,3,4,1,2,3,4,2,3,4,3,4,4};
    for (int pi = wv; pi < 15; pi += 4) {
        float s = 0.f;
        for (int j = ln; j < 512; j += 64) s += h4[pa[pi]][j] * h4[pb[pi]][j];
        for (int off = 32; off > 0; off >>= 1) s += __shfl_down(s, off, 64);
        if (ln == 0) qdotS[pi] = s;
    }
    __syncthreads();

    // ---- parallel QP: lane = mask (1..31 valid), wave 0 only ----
    if (t < 64) {
        const double n = 2048.0;
        double Q[KG][KG], p[KG], eta[KG];
        {
            int idx = 0;
            double dd[KG][KG];
#pragma unroll
            for (int a = 0; a < KG; ++a)
#pragma unroll
                for (int b = a; b < KG; ++b) { dd[a][b] = qdotS[idx]; dd[b][a] = qdotS[idx]; ++idx; }
#pragma unroll
            for (int a = 0; a < KG; ++a)
#pragma unroll
                for (int b = 0; b < KG; ++b) {
                    double qp = (4.0 / n) * (dd[a][b] + ((a == b) ? dd[a][a] : 0.0));
                    Q[a][b] = 2.0 * qp + ((a == b) ? 1e-5 : 0.0);
                }
        }
#pragma unroll
        for (int k = 0; k < KG; ++k) {
            p[k] = -2.0 * (double)hsumS[k] / n;
            eta[k] = sumsS[k] / (n * n);
        }

        const int mask = t;
        const bool valid = (mask >= 1 && mask < 32);
        double beta[KG] = {0, 0, 0, 0, 0};
        double obj = INFINITY;

        if (valid) {
            double m[KG];
#pragma unroll
            for (int k = 0; k < KG; ++k) m[k] = (mask >> k) & 1 ? 1.0 : 0.0;
            double M[6][7];
#pragma unroll
            for (int a = 0; a < 6; ++a)
#pragma unroll
                for (int b = 0; b < 7; ++b) M[a][b] = 0.0;
#pragma unroll
            for (int a = 0; a < KG; ++a) {
#pragma unroll
                for (int b = 0; b < KG; ++b) M[a][b] = m[a] * Q[a][b] * m[b];
                M[a][a] += 1.0 - m[a];
                M[a][KG] = m[a];
                M[KG][a] = m[a];
                M[a][6] = -m[a] * p[a];
            }
            M[KG][6] = 1.0;
#pragma unroll
            for (int col = 0; col < 6; ++col) {
                const double dinv = 1.0 / M[col][col];
#pragma unroll
                for (int rr = 0; rr < 6; ++rr) {
                    if (rr > col) {
                        const double f = M[rr][col] * dinv;
#pragma unroll
                        for (int c = 0; c < 7; ++c)
                            if (c >= col) M[rr][c] -= f * M[col][c];
                    }
                }
            }
            double sol[6];
#pragma unroll
            for (int rr = 5; rr >= 0; --rr) {
                double s = M[rr][6];
#pragma unroll
                for (int c = 0; c < 6; ++c)
                    if (c > rr) s -= M[rr][c] * sol[c];
                sol[rr] = s / M[rr][rr];
            }
#pragma unroll
            for (int k = 0; k < KG; ++k) beta[k] = sol[k] * m[k];
            double o = 0.0;
#pragma unroll
            for (int a = 0; a < KG; ++a) {
                double qb = 0.0;
#pragma unroll
                for (int b = 0; b < KG; ++b) qb += Q[a][b] * beta[b];
                o += 0.5 * beta[a] * qb + p[a] * beta[a];
            }
            bool feas = true;
#pragma unroll
            for (int k = 0; k < KG; ++k) if (!(beta[k] >= -1e-7)) feas = false;
            obj = feas ? o : INFINITY;
        }

        double bobj = obj;
        int blane = valid ? mask : 9999;
        for (int off = 32; off > 0; off >>= 1) {
            const double o2 = __shfl_down(bobj, off, 64);
            const int l2 = __shfl_down(blane, off, 64);
            if (o2 < bobj || (o2 == bobj && l2 < blane)) { bobj = o2; blane = l2; }
        }
        bobj = __shfl(bobj, 0, 64);
        blane = __shfl(blane, 0, 64);
        if (bobj > 1e300) blane = 1;

        if (mask == blane) {
            double o = 0.0;
#pragma unroll
            for (int k = 0; k < KG; ++k) o += eta[k] * beta[k];
            out[0] = (float)o;
        }
    }
}

// ---------------- launch ----------------
extern "C" void kernel_launch(void* const* d_in, const int* in_sizes, int n_in,
                              void* d_out, int out_size, void* d_ws, size_t ws_size,
                              hipStream_t stream) {
    const float* Xs = (const float*)d_in[0];
    const float* Xt = (const float*)d_in[1];
    float* out = (float*)d_out;

    char* ws = (char*)d_ws;
    float* partial = (float*)ws;                       // 528*8 f32 (~17 KB)
    float* nz = (float*)(ws + 32768);                  // 4096 f32
    float* sz = (float*)(ws + 32768 + 16384);          // 4096 f32
    float* h  = (float*)(ws + 65536);                  // 5*1024 f32
    signed char* Zq = (signed char*)(ws + 131072);     // 4096*512 i8 = 2 MB

    prep_kernel<<<256, 256, 0, stream>>>(Xs, Xt, Zq, nz, sz, h);
    gram_kernel<<<NJOBS, 256, 0, stream>>>(Zq, nz, sz, partial);
    finalize_kernel<<<1, 256, 0, stream>>>(partial, h, out);
}

// Round 10
// 30.841 us; speedup vs baseline: 1.3817x; 1.3817x over previous
//
#include <hip/hip_runtime.h>
#include <math.h>

#define NROWS 2048
#define DIMS  512
#define KG    5

// invc[k] = 1/(2*gamma^2), gammas = {2,1,0.5,0.25,0.125} -> {0.125,0.5,2,8,32} (x4 chain)
__device__ __constant__ float c_invc[KG] = {0.125f, 0.5f, 2.0f, 8.0f, 32.0f};

typedef __attribute__((ext_vector_type(4))) int i32x4;

__device__ __forceinline__ void gload_lds16(const void* g, void* l) {
    __builtin_amdgcn_global_load_lds(
        (const __attribute__((address_space(1))) unsigned int*)g,
        (__attribute__((address_space(3))) unsigned int*)l, 16, 0, 0);
}

__device__ __forceinline__ unsigned long long pack8(const float4 v0, const float4 v1, float inv) {
    const float vv[8] = {v0.x, v0.y, v0.z, v0.w, v1.x, v1.y, v1.z, v1.w};
    unsigned long long pk = 0;
#pragma unroll
    for (int e = 0; e < 8; ++e) {
        int q = (int)rintf(vv[e] * inv);
        q = q > 127 ? 127 : (q < -127 ? -127 : q);
        pk |= (unsigned long long)((unsigned)q & 0xffu) << (8 * e);
    }
    return pk;
}

// ============ prep: int8 quantize (per-row scale) + row norms + h pairs ============
// 256 blocks x 256 threads; one wave per pair j: rows {2j,2j+1} of BOTH Xs and Xt.
__global__ void prep_kernel(const float* __restrict__ Xs, const float* __restrict__ Xt,
                            signed char* __restrict__ Xsq, signed char* __restrict__ Xtq,
                            float* __restrict__ ns, float* __restrict__ nt,
                            float* __restrict__ sa, float* __restrict__ st,
                            float* __restrict__ h) {
    const int pairI = blockIdx.x * 4 + (threadIdx.x >> 6);   // 0..1023
    const int lane = threadIdx.x & 63;
    const int i = 2 * pairI, j = i + 1;

    const float* psi = Xs + (size_t)i * DIMS + lane * 8;
    const float* psj = Xs + (size_t)j * DIMS + lane * 8;
    const float* pti = Xt + (size_t)i * DIMS + lane * 8;
    const float* ptj = Xt + (size_t)j * DIMS + lane * 8;
    const float4 a0 = *(const float4*)psi, a1 = *(const float4*)(psi + 4);
    const float4 b0 = *(const float4*)psj, b1 = *(const float4*)(psj + 4);
    const float4 c0 = *(const float4*)pti, c1 = *(const float4*)(pti + 4);
    const float4 d0 = *(const float4*)ptj, d1 = *(const float4*)(ptj + 4);

#define DOT8(u0, u1, v0, v1) (u0.x*v0.x + u0.y*v0.y + u0.z*v0.z + u0.w*v0.w + \
                              u1.x*v1.x + u1.y*v1.y + u1.z*v1.z + u1.w*v1.w)
#define MAX8(u0, u1) fmaxf(fmaxf(fmaxf(fabsf(u0.x), fabsf(u0.y)), fmaxf(fabsf(u0.z), fabsf(u0.w))), \
                           fmaxf(fmaxf(fabsf(u1.x), fabsf(u1.y)), fmaxf(fabsf(u1.z), fabsf(u1.w))))
    float r[8];
    r[0] = DOT8(a0, a1, a0, a1);
    r[1] = DOT8(b0, b1, b0, b1);
    r[2] = DOT8(c0, c1, c0, c1);
    r[3] = DOT8(d0, d1, d0, d1);
    r[4] = DOT8(a0, a1, b0, b1);
    r[5] = DOT8(c0, c1, d0, d1);
    r[6] = DOT8(a0, a1, d0, d1);
    r[7] = DOT8(c0, c1, b0, b1);
    float mx[4] = {MAX8(a0, a1), MAX8(b0, b1), MAX8(c0, c1), MAX8(d0, d1)};
#undef DOT8
#undef MAX8

#pragma unroll
    for (int v = 0; v < 4; ++v)
        for (int off = 32; off > 0; off >>= 1) mx[v] = fmaxf(mx[v], __shfl_xor(mx[v], off, 64));

    float inv[4], scl[4];
#pragma unroll
    for (int v = 0; v < 4; ++v) {
        scl[v] = mx[v] * (1.f / 127.f);
        inv[v] = mx[v] > 0.f ? 127.f / mx[v] : 0.f;
    }

    *(unsigned long long*)(Xsq + (size_t)i * DIMS + lane * 8) = pack8(a0, a1, inv[0]);
    *(unsigned long long*)(Xsq + (size_t)j * DIMS + lane * 8) = pack8(b0, b1, inv[1]);
    *(unsigned long long*)(Xtq + (size_t)i * DIMS + lane * 8) = pack8(c0, c1, inv[2]);
    *(unsigned long long*)(Xtq + (size_t)j * DIMS + lane * 8) = pack8(d0, d1, inv[3]);

#pragma unroll
    for (int v = 0; v < 8; ++v)
        for (int off = 32; off > 0; off >>= 1) r[v] += __shfl_down(r[v], off, 64);

    if (lane == 0) {
        ns[i] = r[0]; ns[j] = r[1]; nt[i] = r[2]; nt[j] = r[3];
        sa[i] = scl[0]; sa[j] = scl[1]; st[i] = scl[2]; st[j] = scl[3];
#pragma unroll
        for (int g = 0; g < KG; ++g) {
            const float ic = c_invc[g];
            h[g * 1024 + pairI] = __expf(-(r[0] + r[1] - 2.f * r[4]) * ic)
                                + __expf(-(r[2] + r[3] - 2.f * r[5]) * ic)
                                - __expf(-(r[0] + r[3] - 2.f * r[6]) * ic)
                                - __expf(-(r[2] + r[1] - 2.f * r[7]) * ic);
        }
    }
}

// ============ gram: int8 MFMA, 128x128 tiles, BK=64, dbuf LDS (32 KB), 2-phase prefetch ============
// (exact R8 structure; partial store is now SoA partial[g][768])
// pair z: 0 = XX (upper tri, x2, diag analytic), 1 = YY (same), 2 = XY (full)
__global__ __launch_bounds__(256, 2) void gram_kernel(const signed char* __restrict__ Xsq,
                                                      const signed char* __restrict__ Xtq,
                                                      const float* __restrict__ ns,
                                                      const float* __restrict__ nt,
                                                      const float* __restrict__ sa,
                                                      const float* __restrict__ st,
                                                      float* __restrict__ partial) {
    const int pair = blockIdx.z;
    const int bx = blockIdx.x, by = blockIdx.y;
    const int bidx = pair * 256 + by * 16 + bx;
    const int tid = threadIdx.x;
    if (pair < 2 && bx < by) {                       // inactive: zero the slot, exit
        if (tid < KG) partial[tid * 768 + bidx] = 0.f;
        return;
    }

    const signed char* A = (pair == 1) ? Xtq : Xsq;
    const signed char* B = (pair == 0) ? Xsq : Xtq;
    const float* na = (pair == 1) ? nt : ns;
    const float* nb = (pair == 0) ? ns : nt;
    const float* sca = (pair == 1) ? st : sa;
    const float* scb = (pair == 0) ? sa : st;
    const int row0 = by * 128, col0 = bx * 128;

    __shared__ signed char Asm[2][128 * 64];         // 2 x 8 KB
    __shared__ signed char Bsm[2][128 * 64];         // 2 x 8 KB

    const int lane = tid & 63;
    const int w = tid >> 6;
    const int wr = w >> 1, wc = w & 1;               // 2x2 waves, 64x64 per wave

    i32x4 acc[4][4] = {};

    const int srow = lane >> 2;                      // staging: row within 16-row group
    const int schunk = lane & 3;                     // staging: 16B chunk (LDS slot)

#define STAGE(buf, kt)                                                              \
    {                                                                               \
        _Pragma("unroll")                                                           \
        for (int q = 0; q < 2; ++q) {                                               \
            const int rbase = q * 64 + w * 16;                                      \
            const int rloc = rbase + srow;                                          \
            const int csrc = (schunk ^ ((rloc >> 1) & 3)) * 16;                     \
            gload_lds16(A + (size_t)(row0 + rloc) * DIMS + (kt) + csrc,             \
                        &Asm[buf][rbase * 64]);                                     \
            gload_lds16(B + (size_t)(col0 + rloc) * DIMS + (kt) + csrc,             \
                        &Bsm[buf][rbase * 64]);                                     \
        }                                                                           \
    }

    STAGE(0, 0);
    __syncthreads();

    const int rl = lane & 15, kq = lane >> 4;
#pragma unroll
    for (int t = 0; t < 8; ++t) {
        const int cur = t & 1;
        if (t < 7) STAGE(cur ^ 1, (t + 1) * 64);     // prefetch issued BEFORE compute

        i32x4 af[4], bv[4];
#pragma unroll
        for (int m = 0; m < 4; ++m) {
            const int ra = wr * 64 + m * 16 + rl;
            af[m] = *(const i32x4*)&Asm[cur][ra * 64 + ((kq ^ ((ra >> 1) & 3)) * 16)];
            const int rb = wc * 64 + m * 16 + rl;
            bv[m] = *(const i32x4*)&Bsm[cur][rb * 64 + ((kq ^ ((rb >> 1) & 3)) * 16)];
        }
#pragma unroll
        for (int m = 0; m < 4; ++m)
#pragma unroll
            for (int n = 0; n < 4; ++n)
                acc[m][n] = __builtin_amdgcn_mfma_i32_16x16x64_i8(af[m], bv[n], acc[m][n], 0, 0, 0);
        __syncthreads();
    }
#undef STAGE

    // epilogue: C/D layout col = lane&15, row = (lane>>4)*4 + reg
    // d = |a|^2 + |b|^2 - 2*sa*sb*idot; screen d>=840 -> all 5 exps underflow f32 -> skip
    float lsum[KG] = {0.f, 0.f, 0.f, 0.f, 0.f};
    const int gcol0 = col0 + wc * 64 + rl;
    const int grow0 = row0 + wr * 64 + kq * 4;
    const bool diagTile = (pair < 2) && (bx == by);
    const float wgt = (pair == 2) ? 1.f : 2.f;

    float colnorm[4], colscale[4];
#pragma unroll
    for (int n = 0; n < 4; ++n) {
        colnorm[n] = nb[gcol0 + n * 16];
        colscale[n] = scb[gcol0 + n * 16];
    }

#pragma unroll
    for (int m = 0; m < 4; ++m) {
        const float4 rn4 = *(const float4*)&na[grow0 + m * 16];
        const float4 rs4 = *(const float4*)&sca[grow0 + m * 16];
        const float rn[4] = {rn4.x, rn4.y, rn4.z, rn4.w};
        const float rs[4] = {rs4.x, rs4.y, rs4.z, rs4.w};
#pragma unroll
        for (int jj = 0; jj < 4; ++jj) {
            const int grow = grow0 + m * 16 + jj;
#pragma unroll
            for (int n = 0; n < 4; ++n) {
                const int gcol = gcol0 + n * 16;
                const float d = rn[jj] + colnorm[n]
                              - 2.f * (rs[jj] * colscale[n]) * (float)acc[m][n][jj];
                if (diagTile && gcol == grow) {
#pragma unroll
                    for (int g = 0; g < KG; ++g) lsum[g] += 1.f;   // exp(0) exactly
                } else if ((!diagTile || gcol > grow) && d < 840.f) {
                    float e = __expf(-d * 0.125f);                 // gamma=2
#pragma unroll
                    for (int g = 0; g < KG; ++g) {
                        lsum[g] += wgt * e;
                        const float e2 = e * e;
                        e = e2 * e2;                               // next gamma (invc x4)
                    }
                }
            }
        }
    }

    // cross-wave reduce + per-block partial store (no atomics), SoA layout
    __shared__ float redf[KG][4];
#pragma unroll
    for (int g = 0; g < KG; ++g) {
        float v = lsum[g];
        for (int off = 32; off > 0; off >>= 1) v += __shfl_down(v, off, 64);
        if (lane == 0) redf[g][w] = v;
    }
    __syncthreads();
    if (tid < KG)
        partial[tid * 768 + bidx] = redf[tid][0] + redf[tid][1] + redf[tid][2] + redf[tid][3];
}

// ---------------- reduce: 25 independent block-reductions (parallel memory phase) ----------------
// qhr[0..14]  = qdot[pi] (Q matrix dots from h pairs)
// qhr[15..19] = hsum[g]
// qhr[20..24] = sums[g] = sXX + sYY - 2*sXY  (pair weights folded)
__global__ void reduce_kernel(const float* __restrict__ partial,
                              const float* __restrict__ h,
                              double* __restrict__ qhr) {
    const int bid = blockIdx.x;
    const int t = threadIdx.x;
    __shared__ double red[4];

    double s = 0.0;
    if (bid < 15) {
        const int pa[15] = {0,0,0,0,0,1,1,1,1,2,2,2,3,3,4};
        const int pb[15] = {0,1,2,3,4,1,2,3,4,2,3,4,3,4,4};
        const float* ha = h + pa[bid] * 1024;
        const float* hb = h + pb[bid] * 1024;
        for (int j = t; j < 512; j += 256) {
            const float va = ha[2 * j] - ha[2 * j + 1];
            const float vb = hb[2 * j] - hb[2 * j + 1];
            s += (double)(va * vb);
        }
    } else if (bid < 20) {
        const float* hg = h + (bid - 15) * 1024;
        for (int j = t; j < 1024; j += 256) s += (double)hg[j];
    } else {
        const int g = bid - 20;
        for (int b = t; b < 768; b += 256) {
            const float wv = (b >> 8) == 2 ? -2.f : 1.f;   // pair weight: +1,+1,-2
            s += (double)(wv * partial[g * 768 + b]);
        }
    }

    for (int off = 32; off > 0; off >>= 1) s += __shfl_down(s, off, 64);
    if ((t & 63) == 0) red[t >> 6] = s;
    __syncthreads();
    if (t == 0) qhr[bid] = red[0] + red[1] + red[2] + red[3];
}

// ---------------- qp: pure-compute parallel QP over 31 masks (1 wave) ----------------
__global__ void qp_kernel(const double* __restrict__ qhr, float* __restrict__ out) {
    const int t = threadIdx.x;   // 64 lanes
    const double n = 2048.0;
    double Q[KG][KG], p[KG], eta[KG];
    {
        int idx = 0;
        double dd[KG][KG];
#pragma unroll
        for (int a = 0; a < KG; ++a)
#pragma unroll
            for (int b = a; b < KG; ++b) { dd[a][b] = qhr[idx]; dd[b][a] = qhr[idx]; ++idx; }
#pragma unroll
        for (int a = 0; a < KG; ++a)
#pragma unroll
            for (int b = 0; b < KG; ++b) {
                double qp = (4.0 / n) * (dd[a][b] + ((a == b) ? dd[a][a] : 0.0));
                Q[a][b] = 2.0 * qp + ((a == b) ? 1e-5 : 0.0);
            }
    }
#pragma unroll
    for (int k = 0; k < KG; ++k) {
        p[k] = -2.0 * qhr[15 + k] / n;
        eta[k] = qhr[20 + k] / (n * n);
    }

    const int mask = t;
    const bool valid = (mask >= 1 && mask < 32);
    double beta[KG] = {0, 0, 0, 0, 0};
    double obj = INFINITY;

    if (valid) {
        double m[KG];
#pragma unroll
        for (int k = 0; k < KG; ++k) m[k] = (mask >> k) & 1 ? 1.0 : 0.0;
        double M[6][7];
#pragma unroll
        for (int a = 0; a < 6; ++a)
#pragma unroll
            for (int b = 0; b < 7; ++b) M[a][b] = 0.0;
#pragma unroll
        for (int a = 0; a < KG; ++a) {
#pragma unroll
            for (int b = 0; b < KG; ++b) M[a][b] = m[a] * Q[a][b] * m[b];
            M[a][a] += 1.0 - m[a];
            M[a][KG] = m[a];
            M[KG][a] = m[a];
            M[a][6] = -m[a] * p[a];
        }
        M[KG][6] = 1.0;
#pragma unroll
        for (int col = 0; col < 6; ++col) {
            const double dinv = 1.0 / M[col][col];
#pragma unroll
            for (int rr = 0; rr < 6; ++rr) {
                if (rr > col) {
                    const double f = M[rr][col] * dinv;
#pragma unroll
                    for (int c = 0; c < 7; ++c)
                        if (c >= col) M[rr][c] -= f * M[col][c];
                }
            }
        }
        double sol[6];
#pragma unroll
        for (int rr = 5; rr >= 0; --rr) {
            double s = M[rr][6];
#pragma unroll
            for (int c = 0; c < 6; ++c)
                if (c > rr) s -= M[rr][c] * sol[c];
            sol[rr] = s / M[rr][rr];
        }
#pragma unroll
        for (int k = 0; k < KG; ++k) beta[k] = sol[k] * m[k];
        double o = 0.0;
#pragma unroll
        for (int a = 0; a < KG; ++a) {
            double qb = 0.0;
#pragma unroll
            for (int b = 0; b < KG; ++b) qb += Q[a][b] * beta[b];
            o += 0.5 * beta[a] * qb + p[a] * beta[a];
        }
        bool feas = true;
#pragma unroll
        for (int k = 0; k < KG; ++k) if (!(beta[k] >= -1e-7)) feas = false;
        obj = feas ? o : INFINITY;
    }

    double bobj = obj;
    int blane = valid ? mask : 9999;
    for (int off = 32; off > 0; off >>= 1) {
        const double o2 = __shfl_down(bobj, off, 64);
        const int l2 = __shfl_down(blane, off, 64);
        if (o2 < bobj || (o2 == bobj && l2 < blane)) { bobj = o2; blane = l2; }
    }
    bobj = __shfl(bobj, 0, 64);
    blane = __shfl(blane, 0, 64);
    if (bobj > 1e300) blane = 1;

    if (mask == blane) {
        double o = 0.0;
#pragma unroll
        for (int k = 0; k < KG; ++k) o += eta[k] * beta[k];
        out[0] = (float)o;
    }
}

// ---------------- launch ----------------
extern "C" void kernel_launch(void* const* d_in, const int* in_sizes, int n_in,
                              void* d_out, int out_size, void* d_ws, size_t ws_size,
                              hipStream_t stream) {
    const float* Xs = (const float*)d_in[0];
    const float* Xt = (const float*)d_in[1];
    float* out = (float*)d_out;

    char* ws = (char*)d_ws;
    float* partial = (float*)ws;                                // 5*768 f32 SoA (15 KB)
    float* ns = (float*)(ws + 16384);                           // 2048 f32
    float* nt = (float*)(ws + 24576);                           // 2048 f32
    float* sa = (float*)(ws + 32768);                           // 2048 f32 row scales Xs
    float* st = (float*)(ws + 40960);                           // 2048 f32 row scales Xt
    float* h  = (float*)(ws + 49152);                           // 5*1024 f32
    double* qhr = (double*)(ws + 98304);                        // 25 doubles
    signed char* Xsq = (signed char*)(ws + 131072);             // 1 MB i8
    signed char* Xtq = (signed char*)(ws + 131072 + 1048576);   // 1 MB i8

    prep_kernel<<<256, 256, 0, stream>>>(Xs, Xt, Xsq, Xtq, ns, nt, sa, st, h);
    gram_kernel<<<dim3(16, 16, 3), 256, 0, stream>>>(Xsq, Xtq, ns, nt, sa, st, partial);
    reduce_kernel<<<25, 256, 0, stream>>>(partial, h, qhr);
    qp_kernel<<<1, 64, 0, stream>>>(qhr, out);
}